// Round 16
// baseline (48.203 us; speedup 1.0000x reference)
//
#include <hip/hip_runtime.h>
#include <math.h>

#define EMB 128
#define WIN 200
#define NT 64
#define BB 128

typedef short bf16x8 __attribute__((ext_vector_type(8)));
typedef float f32x4  __attribute__((ext_vector_type(4)));

__device__ __forceinline__ unsigned pk2bf16(float a, float b) {    // RNE pack
    unsigned ua = __float_as_uint(a), ub = __float_as_uint(b);
    ua = (ua + 0x7FFFu + ((ua >> 16) & 1u)) >> 16;
    ub = (ub + 0x7FFFu + ((ub >> 16) & 1u)) >> 16;
    return ua | (ub << 16);
}
__device__ __forceinline__ float rdlane(float v, int l) {
    return __uint_as_float(__builtin_amdgcn_readlane(__float_as_uint(v), l));
}

// ---------------------------------------------------------------------------
// proj via MFMA (R9/R13-verified fragment code). 128 rows/block, 512 thr =
// 8 waves x 16 rows. blocks [0,64) -> hp (titems); [64,264) -> hq (citems,
// +Wb); block 264 -> mask detect. Outputs fp32 ROW-MAJOR [row][n] (R15:
// coalesced 64B stores; attn reads with zero unpack).
// A,B XOR-swizzled LDS (16B-slot ^= row&7). C map: col=lane&15,
// row=(lane>>4)*4+reg (m89-verified).
// ---------------------------------------------------------------------------
__global__ __launch_bounds__(512, 4) void proj_kernel(
    const float* __restrict__ tvecs, const float* __restrict__ cvecs,
    const int* __restrict__ titems, const int* __restrict__ citems,
    const float* __restrict__ Ww, const float* __restrict__ Wbias,
    const int* __restrict__ mi, int* __restrict__ flag,
    float* __restrict__ hp_out, float* __restrict__ hq_out)
{
    __shared__ __align__(16) ushort s_A[128 * 128];   // 32 KB, swizzled
    __shared__ __align__(16) ushort s_B[128 * 128];   // 32 KB, swizzled
    __shared__ float s_bias[128];
    __shared__ int   sdet;

    const int tid = threadIdx.x;

    if (blockIdx.x == 264) {                          // mask-storage detect
        if (tid == 0) sdet = 0;
        __syncthreads();
        int bad = 0;
        for (int i = tid; i < 6400; i += 512)
            if ((unsigned)mi[i] > 1u) bad = 1;
        if (bad) sdet = 1;
        __syncthreads();
        if (tid == 0) flag[0] = sdet;
        return;
    }

    const bool is_hp = blockIdx.x < 64;
    const float* table = is_hp ? tvecs : cvecs;
    const int*   idx   = is_hp ? titems : citems;
    const int  rbase = (is_hp ? blockIdx.x : (blockIdx.x - 64)) * 128;
    const int  eoff  = is_hp ? 0 : EMB;

    if (tid < 128) s_bias[tid] = Wbias[tid];

    for (int i = tid; i < 4096; i += 512) {           // stage A (gather+cvt)
        int row = i >> 5, j = i & 31;
        float4 v = *(const float4*)&table[(size_t)idx[rbase + row] * 128 + 4 * j];
        uint2 p; p.x = pk2bf16(v.x, v.y); p.y = pk2bf16(v.z, v.w);
        *(uint2*)((char*)s_A + row * 256 + (((j >> 1) ^ (row & 7)) << 4) + (j & 1) * 8) = p;
    }
    for (int i = tid; i < 4096; i += 512) {           // stage B (Ww fp32 + cvt)
        int n = i >> 5, j = i & 31;
        float4 v = *(const float4*)&Ww[n * 256 + eoff + 4 * j];
        uint2 p; p.x = pk2bf16(v.x, v.y); p.y = pk2bf16(v.z, v.w);
        *(uint2*)((char*)s_B + n * 256 + (((j >> 1) ^ (n & 7)) << 4) + (j & 1) * 8) = p;
    }
    __syncthreads();

    const int wid = tid >> 6, l = tid & 63;
    const int rl = l & 15, kg = l >> 4;
    const int r0 = wid * 16;

    f32x4 acc[8];
#pragma unroll
    for (int i = 0; i < 8; ++i) acc[i] = (f32x4){0.f, 0.f, 0.f, 0.f};

    const int arow = r0 + rl;
#pragma unroll
    for (int s = 0; s < 4; ++s) {
        bf16x8 af = *(const bf16x8*)((const char*)s_A
                        + arow * 256 + ((((s << 2) + kg) ^ (arow & 7)) << 4));
#pragma unroll
        for (int nt = 0; nt < 8; ++nt) {
            int bn = nt * 16 + rl;
            bf16x8 bfr = *(const bf16x8*)((const char*)s_B
                            + bn * 256 + ((((s << 2) + kg) ^ (bn & 7)) << 4));
            acc[nt] = __builtin_amdgcn_mfma_f32_16x16x32_bf16(af, bfr, acc[nt], 0, 0, 0);
        }
    }

    // C-write fp32 row-major: row = rbase + r0 + kg*4 + i, col = nt*16 + rl
#pragma unroll
    for (int i = 0; i < 4; ++i) {
        size_t base = (size_t)(rbase + r0 + kg * 4 + i) * 128;
        if (is_hp) {
#pragma unroll
            for (int nt = 0; nt < 8; ++nt)
                hp_out[base + nt * 16 + rl] = acc[nt][i];
        } else {
#pragma unroll
            for (int nt = 0; nt < 8; ++nt) {
                int col = nt * 16 + rl;
                hq_out[base + col] = acc[nt][i] + s_bias[col];
            }
        }
    }
}

// ---------------------------------------------------------------------------
// attn (R12-verified structure): one block per (b, 32-t half), 512 thr =
// 8 waves x 4 t. Compacted hq (64KB fp32) + compacted k rows (64KB fp32)
// staged ONCE per block in LDS; score/softmax/PV from LDS/regs.
// R16 FIX: grid is 256, so swizzle is (bid&7)*32 + (bid>>3) — R15 used *64
// (grid-512 constant), sending b up to 239 >= 128 -> OOB fault.
// m>128 fallback: direct-from-global.
// ---------------------------------------------------------------------------
__global__ __launch_bounds__(512, 2) void attn_kernel(
    const float* __restrict__ cvecs, const int* __restrict__ citems,
    const void* __restrict__ mask_raw, const int* __restrict__ flagp,
    const float* __restrict__ hwg, const float* __restrict__ hp,
    const float* __restrict__ hq, float* __restrict__ outp)
{
    __shared__ __align__(16) float4 s_hq4[32 * 128];  // [nc][w'] 64 KB
    __shared__ __align__(16) float4 s_k4[128 * 32];   // [w'][e4] 64 KB
    __shared__ __align__(16) float  s_hp[32 * 128];   // [lt][n] 16 KB
    __shared__ __align__(16) float  s_hw[128];
    __shared__ int s_ci[WIN];
    __shared__ int s_widx[WIN];
    __shared__ int s_m;

    const int tid  = threadIdx.x;
    const int bid  = blockIdx.x;
    const int swz  = (bid & 7) * 32 + (bid >> 3);     // bijective on [0,256)
    const int b    = swz >> 1;
    const int tb   = (swz & 1) * 32;
    const int lane = tid & 63;
    const int wid  = tid >> 6;
    const int t0   = wid * 4;

    for (int i = tid; i < 1024; i += 512) {
        int t = i >> 5, e4 = i & 31;
        *(float4*)&s_hp[t * 128 + e4 * 4] =
            *(const float4*)&hp[((size_t)(b * 64 + tb + t)) * 128 + e4 * 4];
    }
    if (tid < 128) s_hw[tid] = hwg[tid];
    if (tid < WIN) s_ci[tid] = citems[b * WIN + tid];
    if (wid == 0) {
        const int boolmode = flagp[0];
        const unsigned char* mb = (const unsigned char*)mask_raw;
        const int*           mi = (const int*)mask_raw;
        int base = 0;
#pragma unroll
        for (int r = 0; r < 4; ++r) {
            int w  = r * 64 + lane;
            int mv = 1;
            if (w < WIN) mv = boolmode ? (int)mb[b * WIN + w] : mi[b * WIN + w];
            unsigned long long act = __ballot(mv == 0);
            if (mv == 0)
                s_widx[base + __popcll(act & ((1ull << lane) - 1ull))] = w;
            base += __popcll(act);
        }
        if (lane == 0) s_m = base;
    }
    __syncthreads();

    const int m = s_m;
    const float invn = 1.f / sqrtf(800.f + (float)m);   // 1000 - (200 - m)
    size_t orow = ((size_t)(b * 64 + tb + t0)) * 128;

    if (m == 0) {
#pragma unroll
        for (int j = 0; j < 4; ++j)
            *(float2*)&outp[orow + (size_t)j * 128 + lane * 2] = make_float2(0.f, 0.f);
        return;
    }

    const float4* hq4r = (const float4*)hq + (size_t)b * 200 * 32;  // [w][e4]
    const float4* hp4a = (const float4*)&s_hp[t0 * 128];
    const float4* hw4p = (const float4*)s_hw;
    const float4* cv4  = (const float4*)cvecs;

#define SC(J, K, HV, P)                                                        \
    va[J][K] += hwv.x * fmaxf(HV.x + P.x, 0.f) + hwv.y * fmaxf(HV.y + P.y, 0.f)\
              + hwv.z * fmaxf(HV.z + P.z, 0.f) + hwv.w * fmaxf(HV.w + P.w, 0.f);

    if (m <= 128) {
        // ======================= staged fast path =======================
        {   // hq: [nc][w'] gather once (row-major fp32 source)
            const int w2 = tid & 127, nc0 = tid >> 7;
            if (w2 < m) {
                const int wi = s_widx[w2];
#pragma unroll
                for (int nc = nc0; nc < 32; nc += 4)
                    s_hq4[nc * 128 + w2] = hq4r[(size_t)wi * 32 + nc];
            }
            // k: [w'][e4] gather once (rows coalesced by 32 threads)
            const int e4 = tid & 31, w0 = tid >> 5;
            for (int w2k = w0; w2k < m; w2k += 16) {
                int ci = s_ci[s_widx[w2k]];
                s_k4[w2k * 32 + e4] = cv4[(size_t)ci * 32 + e4];
            }
        }
        __syncthreads();

        float va[4][2];
#pragma unroll
        for (int j = 0; j < 4; ++j) { va[j][0] = 0.f; va[j][1] = 0.f; }

#pragma unroll 2
        for (int nc = 0; nc < 32; ++nc) {
            float4 hv0 = s_hq4[nc * 128 + lane];
            float4 hv1 = s_hq4[nc * 128 + 64 + lane];
            float4 hwv = hw4p[nc];
            float4 p0  = hp4a[0 * 32 + nc];
            float4 p1  = hp4a[1 * 32 + nc];
            float4 p2  = hp4a[2 * 32 + nc];
            float4 p3  = hp4a[3 * 32 + nc];
            SC(0, 0, hv0, p0) SC(0, 1, hv1, p0)
            SC(1, 0, hv0, p1) SC(1, 1, hv1, p1)
            SC(2, 0, hv0, p2) SC(2, 1, hv1, p2)
            SC(3, 0, hv0, p3) SC(3, 1, hv1, p3)
        }

        // softmax over m compacted lanes (2 tiles)
#pragma unroll
        for (int j = 0; j < 4; ++j) {
            float mx = -1e30f;
#pragma unroll
            for (int kt = 0; kt < 2; ++kt) {
                float v = (kt * 64 + lane < m) ? va[j][kt] : -1e30f;
                va[j][kt] = v;
                mx = fmaxf(mx, v);
            }
#pragma unroll
            for (int off = 32; off; off >>= 1) mx = fmaxf(mx, __shfl_xor(mx, off));
            float sum = 0.f;
#pragma unroll
            for (int kt = 0; kt < 2; ++kt) {
                float e = (va[j][kt] <= -1e29f) ? 0.f : __expf(va[j][kt] - mx);
                va[j][kt] = e;
                sum += e;
            }
#pragma unroll
            for (int off = 32; off; off >>= 1) sum += __shfl_xor(sum, off);
            float is = 1.f / sum;
            va[j][0] *= is; va[j][1] *= is;
        }

        // PV from LDS k rows, att via readlane
        float2 po[4];
#pragma unroll
        for (int j = 0; j < 4; ++j) po[j] = make_float2(0.f, 0.f);
        const float2* s_k2 = (const float2*)s_k4;
#pragma unroll
        for (int kt = 0; kt < 2; ++kt) {
            if (kt * 64 < m) {
                const int wn = min(64, m - kt * 64);
                for (int w = 0; w < wn; ++w) {
                    float2 kv = s_k2[(kt * 64 + w) * 64 + lane];
                    float a0 = rdlane(va[0][kt], w);
                    float a1 = rdlane(va[1][kt], w);
                    float a2 = rdlane(va[2][kt], w);
                    float a3 = rdlane(va[3][kt], w);
                    po[0].x += a0 * kv.x; po[0].y += a0 * kv.y;
                    po[1].x += a1 * kv.x; po[1].y += a1 * kv.y;
                    po[2].x += a2 * kv.x; po[2].y += a2 * kv.y;
                    po[3].x += a3 * kv.x; po[3].y += a3 * kv.y;
                }
            }
        }
#pragma unroll
        for (int j = 0; j < 4; ++j)
            *(float2*)&outp[orow + (size_t)j * 128 + lane * 2] =
                make_float2(po[j].x * invn, po[j].y * invn);
    } else {
        // ================== direct fallback (m > 128, rare) ==================
        int wreg[4];
        const int mc = m - 1;
#pragma unroll
        for (int kt = 0; kt < 4; ++kt)
            wreg[kt] = s_widx[min(kt * 64 + lane, mc)];

        float va[4][4];
#pragma unroll
        for (int j = 0; j < 4; ++j)
#pragma unroll
            for (int k = 0; k < 4; ++k) va[j][k] = 0.f;

#pragma unroll 2
        for (int nc = 0; nc < 32; ++nc) {
            float4 hv0 = hq4r[(size_t)wreg[0] * 32 + nc];
            float4 hv1 = hq4r[(size_t)wreg[1] * 32 + nc];
            float4 hv2 = hq4r[(size_t)wreg[2] * 32 + nc];
            float4 hv3 = hq4r[(size_t)wreg[3] * 32 + nc];
            float4 hwv = hw4p[nc];
            float4 p0  = hp4a[0 * 32 + nc];
            float4 p1  = hp4a[1 * 32 + nc];
            float4 p2  = hp4a[2 * 32 + nc];
            float4 p3  = hp4a[3 * 32 + nc];
            SC(0, 0, hv0, p0) SC(0, 1, hv1, p0) SC(0, 2, hv2, p0) SC(0, 3, hv3, p0)
            SC(1, 0, hv0, p1) SC(1, 1, hv1, p1) SC(1, 2, hv2, p1) SC(1, 3, hv3, p1)
            SC(2, 0, hv0, p2) SC(2, 1, hv1, p2) SC(2, 2, hv2, p2) SC(2, 3, hv3, p2)
            SC(3, 0, hv0, p3) SC(3, 1, hv1, p3) SC(3, 2, hv2, p3) SC(3, 3, hv3, p3)
        }

#pragma unroll
        for (int j = 0; j < 4; ++j) {
            float mx = -1e30f;
#pragma unroll
            for (int kt = 0; kt < 4; ++kt) {
                float v = (kt * 64 + lane < m) ? va[j][kt] : -1e30f;
                va[j][kt] = v;
                mx = fmaxf(mx, v);
            }
#pragma unroll
            for (int off = 32; off; off >>= 1) mx = fmaxf(mx, __shfl_xor(mx, off));
            float sum = 0.f;
#pragma unroll
            for (int kt = 0; kt < 4; ++kt) {
                float e = (va[j][kt] <= -1e29f) ? 0.f : __expf(va[j][kt] - mx);
                va[j][kt] = e;
                sum += e;
            }
#pragma unroll
            for (int off = 32; off; off >>= 1) sum += __shfl_xor(sum, off);
            float is = 1.f / sum;
#pragma unroll
            for (int kt = 0; kt < 4; ++kt) va[j][kt] *= is;
        }

        float2 po[4];
#pragma unroll
        for (int j = 0; j < 4; ++j) po[j] = make_float2(0.f, 0.f);
        const char* cvb = (const char*)cvecs;
#pragma unroll
        for (int kt = 0; kt < 4; ++kt) {
            if (kt * 64 < m) {
                const int wn = min(64, m - kt * 64);
                for (int w = 0; w < wn; ++w) {
                    unsigned off = (unsigned)s_ci[s_widx[kt * 64 + w]] * 512u;
                    float2 kv = *(const float2*)(cvb + off + lane * 8);
                    float a0 = rdlane(va[0][kt], w);
                    float a1 = rdlane(va[1][kt], w);
                    float a2 = rdlane(va[2][kt], w);
                    float a3 = rdlane(va[3][kt], w);
                    po[0].x += a0 * kv.x; po[0].y += a0 * kv.y;
                    po[1].x += a1 * kv.x; po[1].y += a1 * kv.y;
                    po[2].x += a2 * kv.x; po[2].y += a2 * kv.y;
                    po[3].x += a3 * kv.x; po[3].y += a3 * kv.y;
                }
            }
        }
#pragma unroll
        for (int j = 0; j < 4; ++j)
            *(float2*)&outp[orow + (size_t)j * 128 + lane * 2] =
                make_float2(po[j].x * invn, po[j].y * invn);
    }
#undef SC
}

// ---------------------------------------------------------------------------
extern "C" void kernel_launch(void* const* d_in, const int* in_sizes, int n_in,
                              void* d_out, int out_size, void* d_ws, size_t ws_size,
                              hipStream_t stream) {
    const float* tvecs = (const float*)d_in[0];
    const float* cvecs = (const float*)d_in[1];
    const float* Ww    = (const float*)d_in[2];
    const float* Wb    = (const float*)d_in[3];
    const float* hw    = (const float*)d_in[4];
    // d_in[5] = h_b : unused (softmax shift-invariance)
    const int* titems  = (const int*)d_in[6];
    const int* citems  = (const int*)d_in[7];
    const void* mask   = d_in[8];
    float* out         = (float*)d_out;

    // ws: flag 256 B | hp (8192x128 f32 = 4 MB) | hq (25600x128 f32 = 13.1 MB)
    const size_t hp_elems = (size_t)BB * NT * 128;
    const size_t hq_elems = (size_t)BB * WIN * 128;
    const size_t needed = 256 + (hp_elems + hq_elems) * 4;
    if (ws_size < needed) return;

    int*   flag  = (int*)d_ws;
    float* hp_ws = (float*)((char*)d_ws + 256);
    float* hq_ws = hp_ws + hp_elems;

    proj_kernel<<<265, 512, 0, stream>>>(tvecs, cvecs, titems, citems,
                                         Ww, Wb, (const int*)mask, flag,
                                         hp_ws, hq_ws);
    attn_kernel<<<BB * 2, 512, 0, stream>>>(cvecs, citems, mask, flag,
                                            hw, hp_ws, hq_ws, out);
}